// Round 9
// baseline (39316.733 us; speedup 1.0000x reference)
//
#include <hip/hip_runtime.h>
#include <math.h>

// Shapes
#define NB   256   // batch N
#define TDIM 87
#define HD   128
#define H3   384
#define NCLS 43

typedef float f32x4 __attribute__((ext_vector_type(4)));

__device__ __forceinline__ float sigmoidf_(float x){ return 1.0f/(1.0f + __expf(-x)); }
__device__ __forceinline__ float tanhf_(float x){ return 1.0f - 2.0f/(1.0f + __expf(2.0f*x)); }
__device__ __forceinline__ float lrelu_(float x){ return x > 0.f ? x : 0.01f*x; }

// volatile-asm global load: cannot be rematerialized/sunk -> value stays register-resident.
__device__ __forceinline__ f32x4 gload4(const float* p_){
  f32x4 r;
  asm volatile("global_load_dwordx4 %0, %1, off" : "=v"(r) : "v"(p_));
  return r;
}
__device__ __forceinline__ float dot4v(float acc, f32x4 a, f32x4 b){
  acc = fmaf(a[0], b[0], acc); acc = fmaf(a[1], b[1], acc);
  acc = fmaf(a[2], b[2], acc); acc = fmaf(a[3], b[3], acc);
  return acc;
}

// ---------------- conv1 + relu + maxpool ----------------
__global__ __launch_bounds__(256) void k_conv1(const float* __restrict__ tce,
    const float* __restrict__ w1, const float* __restrict__ b1,
    float* __restrict__ pool1){
  const int n = blockIdx.x, oc = blockIdx.y;
  __shared__ float xs[21*52];
  __shared__ float ws[32];
  __shared__ float cv[17*48];
  const int tid = threadIdx.x;
  const int oh = tid/12, owc = (tid%12)*4;
  const bool act = tid < 204;
  const float bias = b1[oc];
  float acc[4];
  #pragma unroll
  for (int j=0;j<4;j++) acc[j] = bias;
  const float* xin  = tce + (size_t)(n*TDIM)*1050;
  const float* wrow = w1  + (size_t)oc*TDIM*25;
  for (int ic=0; ic<TDIM; ++ic){
    for (int j=tid; j<1050; j+=256){ xs[(j/50)*52 + (j%50)] = xin[(size_t)ic*1050 + j]; }
    if (tid < 25) ws[tid] = wrow[ic*25 + tid];
    __syncthreads();
    if (act){
      float wreg[25];
      #pragma unroll
      for (int u=0;u<25;u++) wreg[u] = ws[u];
      #pragma unroll
      for (int r=0;r<5;r++){
        const float4* xr = (const float4*)&xs[(oh+r)*52 + owc];
        float4 v0 = xr[0], v1 = xr[1];
        float xv[8] = {v0.x,v0.y,v0.z,v0.w,v1.x,v1.y,v1.z,v1.w};
        #pragma unroll
        for (int c=0;c<5;c++){
          float w = wreg[r*5+c];
          #pragma unroll
          for (int j=0;j<4;j++) acc[j] = fmaf(w, xv[c+j], acc[j]);
        }
      }
    }
    __syncthreads();
  }
  if (act){
    #pragma unroll
    for (int j=0;j<4;j++){
      int ow = owc + j;
      if (ow < 46) cv[oh*48 + ow] = fmaxf(acc[j], 0.0f);
    }
  }
  __syncthreads();
  if (tid < 176){
    int ph = tid/22, pw = tid%22;
    float m = -1e30f;
    #pragma unroll
    for (int r=0;r<3;r++)
      #pragma unroll
      for (int c=0;c<3;c++)
        m = fmaxf(m, cv[(2*ph+r)*48 + (2*pw+c)]);
    pool1[((size_t)(n*TDIM+oc))*176 + tid] = m;
  }
}

// ---------------- conv2 + relu + maxpool -> cnn (256,87,8) ----------------
__global__ __launch_bounds__(128) void k_conv2(const float* __restrict__ pool1,
    const float* __restrict__ w2, const float* __restrict__ b2,
    float* __restrict__ cnn){
  const int n = blockIdx.x, oc = blockIdx.y;
  __shared__ float xs[176];
  __shared__ float ws[32];
  __shared__ float cv[72];
  const int tid = threadIdx.x;
  float a = b2[oc];
  const int oh = tid/18, ow = tid%18;
  const float* xin = pool1 + (size_t)n*TDIM*176;
  const float* wr  = w2 + (size_t)oc*TDIM*25;
  for (int ic=0; ic<TDIM; ++ic){
    for (int j=tid; j<176; j+=128) xs[j] = xin[(size_t)ic*176 + j];
    if (tid < 25) ws[tid] = wr[ic*25 + tid];
    __syncthreads();
    if (tid < 72){
      #pragma unroll
      for (int r=0;r<5;r++)
        #pragma unroll
        for (int c=0;c<5;c++)
          a = fmaf(ws[r*5+c], xs[(oh+r)*22 + (ow+c)], a);
    }
    __syncthreads();
  }
  if (tid < 72) cv[tid] = fmaxf(a, 0.0f);
  __syncthreads();
  if (tid < 8){
    float m = -1e30f;
    #pragma unroll
    for (int r=0;r<3;r++)
      #pragma unroll
      for (int c=0;c<3;c++)
        m = fmaxf(m, cv[r*18 + (2*tid+c)]);
    cnn[((size_t)(n*TDIM+oc))*8 + tid] = m;
  }
}

// ---------------- utterance bi-GRU ----------------
__global__ __launch_bounds__(768,3) void k_utt(
    const float* __restrict__ te, const float* __restrict__ cnn,
    const float* __restrict__ wih_f, const float* __restrict__ whh_f,
    const float* __restrict__ bih_f, const float* __restrict__ bhh_f,
    const float* __restrict__ wih_b, const float* __restrict__ whh_b,
    const float* __restrict__ bih_b, const float* __restrict__ bhh_b,
    float* __restrict__ Hall){
  const int bx  = blockIdx.x;
  const int dir = bx & 1;
  const int n   = bx >> 1;
  const int tid = threadIdx.x;
  const int o   = tid >> 1, kh = tid & 1;
  const float* wih = dir ? wih_b : wih_f;
  const float* whh = dir ? whh_b : whh_f;
  const float* bih = dir ? bih_b : bih_f;
  const float* bhh = dir ? bhh_b : bhh_f;
  float wh[64], wi[32];
  { const float4* wp = (const float4*)(whh + (size_t)o*128 + kh*64);
    #pragma unroll
    for (int q=0;q<16;q++){ float4 v=wp[q]; wh[4*q]=v.x; wh[4*q+1]=v.y; wh[4*q+2]=v.z; wh[4*q+3]=v.w; } }
  #pragma unroll
  for (int k=0;k<32;k++){ int c = kh*32 + k; wi[k] = (c < 58) ? wih[(size_t)o*58 + c] : 0.f; }
  const float bI = bih[o], bH = bhh[o];
  __shared__ float h[128];
  __shared__ float xb[64];
  __shared__ float s_rz[256];
  __shared__ float gin_s[128];
  __shared__ float ghn_s[128];
  if (tid < 128) h[tid] = 0.f;
  if (tid < 64)  xb[tid] = 0.f;
  __syncthreads();
  for (int t=0;t<TDIM;++t){
    const int ttt = dir ? (TDIM-1-t) : t;
    if (tid < 50)      xb[tid] = te[((size_t)n*TDIM + ttt)*50 + tid];
    else if (tid < 58) xb[tid] = cnn[((size_t)n*TDIM + ttt)*8 + (tid - 50)];
    __syncthreads();
    float a0=0,a1=0,a2=0,a3=0;
    const float4* hp = (const float4*)&h[kh*64];
    #pragma unroll
    for (int q=0;q<16;q++){ float4 hv=hp[q];
      a0=fmaf(wh[4*q],hv.x,a0); a1=fmaf(wh[4*q+1],hv.y,a1);
      a2=fmaf(wh[4*q+2],hv.z,a2); a3=fmaf(wh[4*q+3],hv.w,a3); }
    float ah = (a0+a1)+(a2+a3);
    float c0=0,c1=0,c2=0,c3=0;
    const float4* xp = (const float4*)&xb[kh*32];
    #pragma unroll
    for (int q=0;q<8;q++){ float4 xv=xp[q];
      c0=fmaf(wi[4*q],xv.x,c0); c1=fmaf(wi[4*q+1],xv.y,c1);
      c2=fmaf(wi[4*q+2],xv.z,c2); c3=fmaf(wi[4*q+3],xv.w,c3); }
    float ai = (c0+c1)+(c2+c3);
    ah += __shfl_xor(ah, 1);
    ai += __shfl_xor(ai, 1);
    if (kh == 0){
      if (o < 256) s_rz[o] = ah + ai + bI + bH;
      else { gin_s[o-256] = ai + bI; ghn_s[o-256] = ah + bH; }
    }
    __syncthreads();
    if (tid < 128){
      float r  = sigmoidf_(s_rz[tid]);
      float z  = sigmoidf_(s_rz[128+tid]);
      float nn = tanhf_(gin_s[tid] + r*ghn_s[tid]);
      h[tid] = (1.f - z)*nn + z*h[tid];
    }
    __syncthreads();
  }
  if (tid < 128) Hall[(size_t)n*256 + dir*128 + tid] = h[tid];
}

// ---------------- prep ----------------
__global__ __launch_bounds__(256) void k_prep(const float* __restrict__ Hall,
    const float* __restrict__ ctx_w1, const float* __restrict__ proj_w,
    float* __restrict__ a_all, float* __restrict__ s_all){
  const int i = blockIdx.x; const int tid = threadIdx.x;
  __shared__ float hr[256];
  __shared__ float red[2];
  hr[tid] = Hall[(size_t)i*256 + tid];
  __syncthreads();
  if (tid < 128){
    const float4* w  = (const float4*)(ctx_w1 + (size_t)tid*256);
    const float4* hp = (const float4*)hr;
    float a0=0,a1=0,a2=0,a3=0;
    #pragma unroll 8
    for (int q=0;q<64;q++){ float4 wv=w[q], hv=hp[q];
      a0=fmaf(wv.x,hv.x,a0); a1=fmaf(wv.y,hv.y,a1); a2=fmaf(wv.z,hv.z,a2); a3=fmaf(wv.w,hv.w,a3); }
    a_all[(size_t)i*128 + tid] = (a0+a1)+(a2+a3);
  } else {
    const int k = tid - 128;
    float p = hr[k]*proj_w[k] + hr[k+128]*proj_w[k+128];
    #pragma unroll
    for (int off=32; off; off>>=1) p += __shfl_xor(p, off);
    if ((tid & 63) == 0) red[(tid-128)>>6] = p;
  }
  __syncthreads();
  if (tid == 0) s_all[i] = red[0] + red[1];
}

// ---------------- ctx scan v9: 256 threads / 4 waves, 2 rows/thread, 192 pinned floats ----------------
// Invariant attacked: LDS register-delivery (64KB/cell at 1-row/thread, ~64 ds_read_b128).
// 2 rows/thread halves it (32 instr/cell). Divergent tail (v5-proven) -> ONE barrier/cell,
// no gate-LDS roundtrip. launch_bounds(256,1): 512-VGPR budget, ~280 used, 1 wave/SIMD.
__global__ __launch_bounds__(256,1) void k_ctx(
    const float* __restrict__ cg_wih_f, const float* __restrict__ cg_whh_f,
    const float* __restrict__ cg_bih_f, const float* __restrict__ cg_bhh_f,
    const float* __restrict__ cg_wih_b, const float* __restrict__ cg_whh_b,
    const float* __restrict__ cg_bih_b, const float* __restrict__ cg_bhh_b,
    const float* __restrict__ ctx_w2, const float* __restrict__ ctx_b2,
    const float* __restrict__ ctx_w3, const float* __restrict__ proj_b,
    const float* __restrict__ gx0,
    const float* __restrict__ a_all, const float* __restrict__ s_all,
    float* __restrict__ one_d_g, int* __restrict__ flags,
    float* __restrict__ feats){
  const int blk = blockIdx.x;
  const bool isF = blk < 2;
  const int d   = blk & 1;
  const int tid = threadIdx.x;
  const int p2  = tid >> 2;      // row pair: rows {p2, p2+64}
  const int kq  = tid & 3;       // K-quarter: 32 floats
  const float* whh = isF ? cg_whh_f : cg_whh_b;
  const float* wih = isF ? cg_wih_f : cg_wih_b;
  const float* bih = isF ? cg_bih_f : cg_bih_b;
  const float* bhh = isF ? cg_bhh_f : cg_bhh_b;
  const int rA = p2, rB = p2 + 64;

  // ---- asm-pinned stationary weights: 48 f32x4 = 192 floats (2 rows x 3 gates x 32 K)
  const float* bra = whh + (size_t)(      rA)*128 + kq*32;
  const float* bza = whh + (size_t)(128 + rA)*128 + kq*32;
  const float* bna = whh + (size_t)(256 + rA)*128 + kq*32;
  const float* brb = whh + (size_t)(      rB)*128 + kq*32;
  const float* bzb = whh + (size_t)(128 + rB)*128 + kq*32;
  const float* bnb = whh + (size_t)(256 + rB)*128 + kq*32;
  f32x4 wra0=gload4(bra),    wra1=gload4(bra+4),  wra2=gload4(bra+8),  wra3=gload4(bra+12);
  f32x4 wra4=gload4(bra+16), wra5=gload4(bra+20), wra6=gload4(bra+24), wra7=gload4(bra+28);
  f32x4 wza0=gload4(bza),    wza1=gload4(bza+4),  wza2=gload4(bza+8),  wza3=gload4(bza+12);
  f32x4 wza4=gload4(bza+16), wza5=gload4(bza+20), wza6=gload4(bza+24), wza7=gload4(bza+28);
  f32x4 wna0=gload4(bna),    wna1=gload4(bna+4),  wna2=gload4(bna+8),  wna3=gload4(bna+12);
  f32x4 wna4=gload4(bna+16), wna5=gload4(bna+20), wna6=gload4(bna+24), wna7=gload4(bna+28);
  f32x4 wrb0=gload4(brb),    wrb1=gload4(brb+4),  wrb2=gload4(brb+8),  wrb3=gload4(brb+12);
  f32x4 wrb4=gload4(brb+16), wrb5=gload4(brb+20), wrb6=gload4(brb+24), wrb7=gload4(brb+28);
  f32x4 wzb0=gload4(bzb),    wzb1=gload4(bzb+4),  wzb2=gload4(bzb+8),  wzb3=gload4(bzb+12);
  f32x4 wzb4=gload4(bzb+16), wzb5=gload4(bzb+20), wzb6=gload4(bzb+24), wzb7=gload4(bzb+28);
  f32x4 wnb0=gload4(bnb),    wnb1=gload4(bnb+4),  wnb2=gload4(bnb+8),  wnb3=gload4(bnb+12);
  f32x4 wnb4=gload4(bnb+16), wnb5=gload4(bnb+20), wnb6=gload4(bnb+24), wnb7=gload4(bnb+28);
  asm volatile("s_waitcnt vmcnt(0)" ::: "memory");
  __builtin_amdgcn_sched_barrier(0);

  // ---- tail scalars (used by kq==0 lanes), keep-alive to block remat into the loop
  float wirA = wih[rA], wizA = wih[128+rA], winA = wih[256+rA];
  float brA_ = bih[rA]      + bhh[rA];
  float bzA_ = bih[128+rA]  + bhh[128+rA];
  float bnA_ = bih[256+rA];
  float bhnA = bhh[256+rA];
  float wirB = wih[rB], wizB = wih[128+rB], winB = wih[256+rB];
  float brB_ = bih[rB]      + bhh[rB];
  float bzB_ = bih[128+rB]  + bhh[128+rB];
  float bnB_ = bih[256+rB];
  float bhnB = bhh[256+rB];
  float pb   = proj_b[0];
  asm volatile("" : "+v"(wirA), "+v"(wizA), "+v"(winA), "+v"(brA_), "+v"(bzA_),
                    "+v"(bnA_), "+v"(bhnA), "+v"(wirB), "+v"(wizB), "+v"(winB),
                    "+v"(brB_), "+v"(bzB_), "+v"(bnB_), "+v"(bhnB), "+v"(pb));

  __shared__ float hl[2][160];     // 8 chunks of 16 floats, stride 20 (conflict-free), dbuf
  __shared__ float one_d_s[128];
  __shared__ float T_s[160];       // stride-20 chunk layout
  __shared__ float S_s[128];
  __shared__ float red_s[2];

  const float* gsrc = gx0 + (size_t)((isF ? 0 : 2) + d)*128;
  float hmA = gsrc[rA], hmB = gsrc[rB];      // live in kq==0 lanes
  if (tid < 128) hl[0][(tid>>4)*20 + (tid&15)] = gsrc[tid];
  __syncthreads();

  const int chA = (rA>>4)*20 + (rA&15);
  const int chB = (rB>>4)*20 + (rB&15);
  const int kb  = kq*40;                    // base of K-slice in chunk layout

  for (int i=0;i<NB;++i){
    if (isF){
      // ---- attention (plain loads; runs once per outer step). h is in hl[0].
      {
        const float4* w2a = (const float4*)(ctx_w2 + (size_t)rA*128 + kq*32);
        const float4* w2b = (const float4*)(ctx_w2 + (size_t)rB*128 + kq*32);
        const f32x4* hA = (const f32x4*)&hl[0][kb];
        const f32x4* hB = (const f32x4*)&hl[0][kb+20];
        f32x4 q0=hA[0],q1=hA[1],q2=hA[2],q3=hA[3];
        f32x4 q4=hB[0],q5=hB[1],q6=hB[2],q7=hB[3];
        f32x4 qq[8] = {q0,q1,q2,q3,q4,q5,q6,q7};
        float sa=0, sb=0;
        #pragma unroll
        for (int q=0;q<8;q++){
          float4 wv = w2a[q];
          f32x4 w4 = {wv.x,wv.y,wv.z,wv.w};
          sa = dot4v(sa, w4, qq[q]);
        }
        #pragma unroll
        for (int q=0;q<8;q++){
          float4 wv = w2b[q];
          f32x4 w4 = {wv.x,wv.y,wv.z,wv.w};
          sb = dot4v(sb, w4, qq[q]);
        }
        sa += __shfl_xor(sa,1); sa += __shfl_xor(sa,2);
        sb += __shfl_xor(sb,1); sb += __shfl_xor(sb,2);
        if (kq == 0){
          T_s[chA] = tanhf_(a_all[(size_t)i*128 + rA] + sa + ctx_b2[rA]);
          T_s[chB] = tanhf_(a_all[(size_t)i*128 + rB] + sb + ctx_b2[rB]);
        }
      }
      __syncthreads();
      {
        const float4* w3a = (const float4*)(ctx_w3 + (size_t)rA*128 + kq*32);
        const float4* w3b = (const float4*)(ctx_w3 + (size_t)rB*128 + kq*32);
        const f32x4* tA = (const f32x4*)&T_s[kb];
        const f32x4* tB = (const f32x4*)&T_s[kb+20];
        f32x4 t0=tA[0],t1=tA[1],t2=tA[2],t3=tA[3];
        f32x4 t4=tB[0],t5=tB[1],t6=tB[2],t7=tB[3];
        f32x4 tt[8] = {t0,t1,t2,t3,t4,t5,t6,t7};
        float sa=0, sb=0;
        #pragma unroll
        for (int q=0;q<8;q++){
          float4 wv = w3a[q];
          f32x4 w4 = {wv.x,wv.y,wv.z,wv.w};
          sa = dot4v(sa, w4, tt[q]);
        }
        #pragma unroll
        for (int q=0;q<8;q++){
          float4 wv = w3b[q];
          f32x4 w4 = {wv.x,wv.y,wv.z,wv.w};
          sb = dot4v(sb, w4, tt[q]);
        }
        sa += __shfl_xor(sa,1); sa += __shfl_xor(sa,2);
        sb += __shfl_xor(sb,1); sb += __shfl_xor(sb,2);
        if (kq == 0){ S_s[rA] = sa; S_s[rB] = sb; }
      }
      __syncthreads();
      if (tid < 64){
        float m = fmaxf(S_s[tid], S_s[tid+64]);
        #pragma unroll
        for (int off=32; off; off>>=1) m = fmaxf(m, __shfl_xor(m, off));
        if (tid == 0) red_s[0] = m;
      }
      __syncthreads();
      if (tid < 128) S_s[tid] = __expf(S_s[tid] - red_s[0]);
      __syncthreads();
      if (tid < 64){
        float s = S_s[tid] + S_s[tid+64];
        #pragma unroll
        for (int off=32; off; off>>=1) s += __shfl_xor(s, off);
        if (tid == 0) red_s[1] = s;
      }
      __syncthreads();
      if (tid < 128){
        float v = (S_s[tid] / red_s[1]) * s_all[i] + pb;
        one_d_s[tid] = v;
        __hip_atomic_store(&one_d_g[((size_t)d*NB + i)*128 + tid], v,
                           __ATOMIC_RELAXED, __HIP_MEMORY_SCOPE_AGENT);
      }
      __syncthreads();
      if (tid == 0){
        __threadfence();
        __hip_atomic_store(&flags[d], i+1, __ATOMIC_RELEASE, __HIP_MEMORY_SCOPE_AGENT);
      }
    } else {
      if (tid == 0){
        while (__hip_atomic_load(&flags[d], __ATOMIC_ACQUIRE, __HIP_MEMORY_SCOPE_AGENT) < i+1){
          __builtin_amdgcn_s_sleep(8);
        }
      }
      __syncthreads();
      if (tid < 128)
        one_d_s[tid] = __hip_atomic_load(&one_d_g[((size_t)d*NB + i)*128 + tid],
                                         __ATOMIC_RELAXED, __HIP_MEMORY_SCOPE_AGENT);
      __syncthreads();
    }
    // ---- inner GRU: 128 cells, ONE barrier each (dbuf h), divergent tail in kq==0
    for (int tc=0; tc<128; ++tc){
      const float* hcur = hl[tc & 1];
      float*       hnxt = hl[(tc & 1) ^ 1];
      const f32x4* hA = (const f32x4*)&hcur[kb];
      const f32x4* hB = (const f32x4*)&hcur[kb+20];
      f32x4 h0=hA[0],h1=hA[1],h2=hA[2],h3=hA[3];
      f32x4 h4=hB[0],h5=hB[1],h6=hB[2],h7=hB[3];
      float ra1=0,ra2=0, za1=0,za2=0, na1=0,na2=0;
      float rb1=0,rb2=0, zb1=0,zb2=0, nb1=0,nb2=0;
      ra1=dot4v(ra1,wra0,h0); ra1=dot4v(ra1,wra1,h1); ra1=dot4v(ra1,wra2,h2); ra1=dot4v(ra1,wra3,h3);
      ra2=dot4v(ra2,wra4,h4); ra2=dot4v(ra2,wra5,h5); ra2=dot4v(ra2,wra6,h6); ra2=dot4v(ra2,wra7,h7);
      za1=dot4v(za1,wza0,h0); za1=dot4v(za1,wza1,h1); za1=dot4v(za1,wza2,h2); za1=dot4v(za1,wza3,h3);
      za2=dot4v(za2,wza4,h4); za2=dot4v(za2,wza5,h5); za2=dot4v(za2,wza6,h6); za2=dot4v(za2,wza7,h7);
      na1=dot4v(na1,wna0,h0); na1=dot4v(na1,wna1,h1); na1=dot4v(na1,wna2,h2); na1=dot4v(na1,wna3,h3);
      na2=dot4v(na2,wna4,h4); na2=dot4v(na2,wna5,h5); na2=dot4v(na2,wna6,h6); na2=dot4v(na2,wna7,h7);
      rb1=dot4v(rb1,wrb0,h0); rb1=dot4v(rb1,wrb1,h1); rb1=dot4v(rb1,wrb2,h2); rb1=dot4v(rb1,wrb3,h3);
      rb2=dot4v(rb2,wrb4,h4); rb2=dot4v(rb2,wrb5,h5); rb2=dot4v(rb2,wrb6,h6); rb2=dot4v(rb2,wrb7,h7);
      zb1=dot4v(zb1,wzb0,h0); zb1=dot4v(zb1,wzb1,h1); zb1=dot4v(zb1,wzb2,h2); zb1=dot4v(zb1,wzb3,h3);
      zb2=dot4v(zb2,wzb4,h4); zb2=dot4v(zb2,wzb5,h5); zb2=dot4v(zb2,wzb6,h6); zb2=dot4v(zb2,wzb7,h7);
      nb1=dot4v(nb1,wnb0,h0); nb1=dot4v(nb1,wnb1,h1); nb1=dot4v(nb1,wnb2,h2); nb1=dot4v(nb1,wnb3,h3);
      nb2=dot4v(nb2,wnb4,h4); nb2=dot4v(nb2,wnb5,h5); nb2=dot4v(nb2,wnb6,h6); nb2=dot4v(nb2,wnb7,h7);
      float arA = ra1+ra2, azA = za1+za2, anA = na1+na2;
      float arB = rb1+rb2, azB = zb1+zb2, anB = nb1+nb2;
      arA += __shfl_xor(arA,1); arA += __shfl_xor(arA,2);
      azA += __shfl_xor(azA,1); azA += __shfl_xor(azA,2);
      anA += __shfl_xor(anA,1); anA += __shfl_xor(anA,2);
      arB += __shfl_xor(arB,1); arB += __shfl_xor(arB,2);
      azB += __shfl_xor(azB,1); azB += __shfl_xor(azB,2);
      anB += __shfl_xor(anB,1); anB += __shfl_xor(anB,2);
      if (kq == 0){
        float x = one_d_s[isF ? tc : 127-tc];
        float r  = sigmoidf_(fmaf(x, wirA, brA_) + arA);
        float z  = sigmoidf_(fmaf(x, wizA, bzA_) + azA);
        float nn = tanhf_(fmaf(x, winA, bnA_) + r*(anA + bhnA));
        hmA = (1.f - z)*nn + z*hmA;
        hnxt[chA] = hmA;
        r  = sigmoidf_(fmaf(x, wirB, brB_) + arB);
        z  = sigmoidf_(fmaf(x, wizB, bzB_) + azB);
        nn = tanhf_(fmaf(x, winB, bnB_) + r*(anB + bhnB));
        hmB = (1.f - z)*nn + z*hmB;
        hnxt[chB] = hmB;
      }
      __syncthreads();
    }
    if (kq == 0){
      const int off = isF ? d*128 : 256 + d*128;
      feats[(size_t)i*512 + off + rA] = hmA;
      feats[(size_t)i*512 + off + rB] = hmB;
    }
    __syncthreads();
  }
}

// ---------------- classifier ----------------
__global__ __launch_bounds__(256) void k_cls(const float* __restrict__ feats,
    const float* __restrict__ w1, const float* __restrict__ b1,
    const float* __restrict__ w2, const float* __restrict__ b2,
    const float* __restrict__ w3, const float* __restrict__ b3,
    float* __restrict__ out){
  const int n = blockIdx.x; const int tid = threadIdx.x;
  __shared__ float fr[512];
  __shared__ float h1s[256];
  __shared__ float h2s[128];
  fr[tid]       = feats[(size_t)n*512 + tid];
  fr[tid+256]   = feats[(size_t)n*512 + 256 + tid];
  __syncthreads();
  {
    const float4* w  = (const float4*)(w1 + (size_t)tid*512);
    const float4* fp = (const float4*)fr;
    float a0=0,a1=0,a2=0,a3=0;
    #pragma unroll 8
    for (int q=0;q<128;q++){ float4 wv=w[q], fv=fp[q];
      a0=fmaf(wv.x,fv.x,a0); a1=fmaf(wv.y,fv.y,a1); a2=fmaf(wv.z,fv.z,a2); a3=fmaf(wv.w,fv.w,a3); }
    h1s[tid] = lrelu_(b1[tid] + (a0+a1)+(a2+a3));
  }
  __syncthreads();
  if (tid < 128){
    const float4* w  = (const float4*)(w2 + (size_t)tid*256);
    const float4* fp = (const float4*)h1s;
    float a0=0,a1=0,a2=0,a3=0;
    #pragma unroll 8
    for (int q=0;q<64;q++){ float4 wv=w[q], fv=fp[q];
      a0=fmaf(wv.x,fv.x,a0); a1=fmaf(wv.y,fv.y,a1); a2=fmaf(wv.z,fv.z,a2); a3=fmaf(wv.w,fv.w,a3); }
    h2s[tid] = lrelu_(b2[tid] + (a0+a1)+(a2+a3));
  }
  __syncthreads();
  if (tid < NCLS){
    const float4* w  = (const float4*)(w3 + (size_t)tid*128);
    const float4* fp = (const float4*)h2s;
    float a0=0,a1=0,a2=0,a3=0;
    #pragma unroll 8
    for (int q=0;q<32;q++){ float4 wv=w[q], fv=fp[q];
      a0=fmaf(wv.x,fv.x,a0); a1=fmaf(wv.y,fv.y,a1); a2=fmaf(wv.z,fv.z,a2); a3=fmaf(wv.w,fv.w,a3); }
    out[(size_t)n*NCLS + tid] = b3[tid] + (a0+a1)+(a2+a3);
  }
}

// ---------------- workspace layout (bytes) ----------------
#define OFF_FLAGS  0u
#define OFF_SALL   512u
#define OFF_AALL   2048u
#define OFF_ONED   133632u
#define OFF_HALL   395776u
#define OFF_FEATS  657920u
#define OFF_CNN    1182208u
#define OFF_POOL1  1894912u

extern "C" void kernel_launch(void* const* d_in, const int* in_sizes, int n_in,
                              void* d_out, int out_size, void* d_ws, size_t ws_size,
                              hipStream_t stream){
  const float* te   = (const float*)d_in[0];
  const float* tce  = (const float*)d_in[1];
  const float* c1w  = (const float*)d_in[2];
  const float* c1b  = (const float*)d_in[3];
  const float* c2w  = (const float*)d_in[4];
  const float* c2b  = (const float*)d_in[5];
  const float* uwif = (const float*)d_in[6];
  const float* uwhf = (const float*)d_in[7];
  const float* ubif = (const float*)d_in[8];
  const float* ubhf = (const float*)d_in[9];
  const float* uwib = (const float*)d_in[10];
  const float* uwhb = (const float*)d_in[11];
  const float* ubib = (const float*)d_in[12];
  const float* ubhb = (const float*)d_in[13];
  const float* cw1  = (const float*)d_in[14];
  const float* cw2  = (const float*)d_in[15];
  const float* cb2  = (const float*)d_in[16];
  const float* cw3  = (const float*)d_in[17];
  const float* pw   = (const float*)d_in[18];
  const float* pbb  = (const float*)d_in[19];
  const float* gx0  = (const float*)d_in[20];
  const float* gwif = (const float*)d_in[21];
  const float* gwhf = (const float*)d_in[22];
  const float* gbif = (const float*)d_in[23];
  const float* gbhf = (const float*)d_in[24];
  const float* gwib = (const float*)d_in[25];
  const float* gwhb = (const float*)d_in[26];
  const float* gbib = (const float*)d_in[27];
  const float* gbhb = (const float*)d_in[28];
  const float* clw1 = (const float*)d_in[29];
  const float* clb1 = (const float*)d_in[30];
  const float* clw2 = (const float*)d_in[31];
  const float* clb2 = (const float*)d_in[32];
  const float* clw3 = (const float*)d_in[33];
  const float* clb3 = (const float*)d_in[34];
  float* out = (float*)d_out;
  char* ws = (char*)d_ws;
  int*   flags = (int*)  (ws + OFF_FLAGS);
  float* s_all = (float*)(ws + OFF_SALL);
  float* a_all = (float*)(ws + OFF_AALL);
  float* one_d = (float*)(ws + OFF_ONED);
  float* Hall  = (float*)(ws + OFF_HALL);
  float* feats = (float*)(ws + OFF_FEATS);
  float* cnn   = (float*)(ws + OFF_CNN);
  float* pool1 = (float*)(ws + OFF_POOL1);

  hipMemsetAsync(flags, 0, 64, stream);
  k_conv1<<<dim3(NB, TDIM), 256, 0, stream>>>(tce, c1w, c1b, pool1);
  k_conv2<<<dim3(NB, TDIM), 128, 0, stream>>>(pool1, c2w, c2b, cnn);
  k_utt<<<512, 768, 0, stream>>>(te, cnn, uwif, uwhf, ubif, ubhf,
                                 uwib, uwhb, ubib, ubhb, Hall);
  k_prep<<<NB, 256, 0, stream>>>(Hall, cw1, pw, a_all, s_all);
  k_ctx<<<4, 256, 0, stream>>>(gwif, gwhf, gbif, gbhf, gwib, gwhb, gbib, gbhb,
                               cw2, cb2, cw3, pbb, gx0, a_all, s_all,
                               one_d, flags, feats);
  k_cls<<<NB, 256, 0, stream>>>(feats, clw1, clb1, clw2, clb2, clw3, clb3, out);
}

// Round 10
// 24207.849 us; speedup vs baseline: 1.6241x; 1.6241x over previous
//
#include <hip/hip_runtime.h>
#include <math.h>

// Shapes
#define NB   256   // batch N
#define TDIM 87
#define HD   128
#define H3   384
#define NCLS 43

typedef float f32x4 __attribute__((ext_vector_type(4)));
typedef float f32x2 __attribute__((ext_vector_type(2)));

__device__ __forceinline__ float sigmoidf_(float x){ return 1.0f/(1.0f + __expf(-x)); }
__device__ __forceinline__ float tanhf_(float x){ return 1.0f - 2.0f/(1.0f + __expf(2.0f*x)); }
__device__ __forceinline__ float lrelu_(float x){ return x > 0.f ? x : 0.01f*x; }

// volatile-asm global load: cannot be rematerialized/sunk -> value stays register-resident.
__device__ __forceinline__ f32x4 gload4(const float* p_){
  f32x4 r;
  asm volatile("global_load_dwordx4 %0, %1, off" : "=v"(r) : "v"(p_));
  return r;
}
__device__ __forceinline__ float dot4v(float acc, f32x4 a, f32x4 b){
  acc = fmaf(a[0], b[0], acc); acc = fmaf(a[1], b[1], acc);
  acc = fmaf(a[2], b[2], acc); acc = fmaf(a[3], b[3], acc);
  return acc;
}

// ---------------- conv1 + relu + maxpool ----------------
__global__ __launch_bounds__(256) void k_conv1(const float* __restrict__ tce,
    const float* __restrict__ w1, const float* __restrict__ b1,
    float* __restrict__ pool1){
  const int n = blockIdx.x, oc = blockIdx.y;
  __shared__ float xs[21*52];
  __shared__ float ws[32];
  __shared__ float cv[17*48];
  const int tid = threadIdx.x;
  const int oh = tid/12, owc = (tid%12)*4;
  const bool act = tid < 204;
  const float bias = b1[oc];
  float acc[4];
  #pragma unroll
  for (int j=0;j<4;j++) acc[j] = bias;
  const float* xin  = tce + (size_t)(n*TDIM)*1050;
  const float* wrow = w1  + (size_t)oc*TDIM*25;
  for (int ic=0; ic<TDIM; ++ic){
    for (int j=tid; j<1050; j+=256){ xs[(j/50)*52 + (j%50)] = xin[(size_t)ic*1050 + j]; }
    if (tid < 25) ws[tid] = wrow[ic*25 + tid];
    __syncthreads();
    if (act){
      float wreg[25];
      #pragma unroll
      for (int u=0;u<25;u++) wreg[u] = ws[u];
      #pragma unroll
      for (int r=0;r<5;r++){
        const float4* xr = (const float4*)&xs[(oh+r)*52 + owc];
        float4 v0 = xr[0], v1 = xr[1];
        float xv[8] = {v0.x,v0.y,v0.z,v0.w,v1.x,v1.y,v1.z,v1.w};
        #pragma unroll
        for (int c=0;c<5;c++){
          float w = wreg[r*5+c];
          #pragma unroll
          for (int j=0;j<4;j++) acc[j] = fmaf(w, xv[c+j], acc[j]);
        }
      }
    }
    __syncthreads();
  }
  if (act){
    #pragma unroll
    for (int j=0;j<4;j++){
      int ow = owc + j;
      if (ow < 46) cv[oh*48 + ow] = fmaxf(acc[j], 0.0f);
    }
  }
  __syncthreads();
  if (tid < 176){
    int ph = tid/22, pw = tid%22;
    float m = -1e30f;
    #pragma unroll
    for (int r=0;r<3;r++)
      #pragma unroll
      for (int c=0;c<3;c++)
        m = fmaxf(m, cv[(2*ph+r)*48 + (2*pw+c)]);
    pool1[((size_t)(n*TDIM+oc))*176 + tid] = m;
  }
}

// ---------------- conv2 + relu + maxpool -> cnn (256,87,8) ----------------
__global__ __launch_bounds__(128) void k_conv2(const float* __restrict__ pool1,
    const float* __restrict__ w2, const float* __restrict__ b2,
    float* __restrict__ cnn){
  const int n = blockIdx.x, oc = blockIdx.y;
  __shared__ float xs[176];
  __shared__ float ws[32];
  __shared__ float cv[72];
  const int tid = threadIdx.x;
  float a = b2[oc];
  const int oh = tid/18, ow = tid%18;
  const float* xin = pool1 + (size_t)n*TDIM*176;
  const float* wr  = w2 + (size_t)oc*TDIM*25;
  for (int ic=0; ic<TDIM; ++ic){
    for (int j=tid; j<176; j+=128) xs[j] = xin[(size_t)ic*176 + j];
    if (tid < 25) ws[tid] = wr[ic*25 + tid];
    __syncthreads();
    if (tid < 72){
      #pragma unroll
      for (int r=0;r<5;r++)
        #pragma unroll
        for (int c=0;c<5;c++)
          a = fmaf(ws[r*5+c], xs[(oh+r)*22 + (ow+c)], a);
    }
    __syncthreads();
  }
  if (tid < 72) cv[tid] = fmaxf(a, 0.0f);
  __syncthreads();
  if (tid < 8){
    float m = -1e30f;
    #pragma unroll
    for (int r=0;r<3;r++)
      #pragma unroll
      for (int c=0;c<3;c++)
        m = fmaxf(m, cv[r*18 + (2*tid+c)]);
    cnn[((size_t)(n*TDIM+oc))*8 + tid] = m;
  }
}

// ---------------- utterance bi-GRU ----------------
__global__ __launch_bounds__(768,3) void k_utt(
    const float* __restrict__ te, const float* __restrict__ cnn,
    const float* __restrict__ wih_f, const float* __restrict__ whh_f,
    const float* __restrict__ bih_f, const float* __restrict__ bhh_f,
    const float* __restrict__ wih_b, const float* __restrict__ whh_b,
    const float* __restrict__ bih_b, const float* __restrict__ bhh_b,
    float* __restrict__ Hall){
  const int bx  = blockIdx.x;
  const int dir = bx & 1;
  const int n   = bx >> 1;
  const int tid = threadIdx.x;
  const int o   = tid >> 1, kh = tid & 1;
  const float* wih = dir ? wih_b : wih_f;
  const float* whh = dir ? whh_b : whh_f;
  const float* bih = dir ? bih_b : bih_f;
  const float* bhh = dir ? bhh_b : bhh_f;
  float wh[64], wi[32];
  { const float4* wp = (const float4*)(whh + (size_t)o*128 + kh*64);
    #pragma unroll
    for (int q=0;q<16;q++){ float4 v=wp[q]; wh[4*q]=v.x; wh[4*q+1]=v.y; wh[4*q+2]=v.z; wh[4*q+3]=v.w; } }
  #pragma unroll
  for (int k=0;k<32;k++){ int c = kh*32 + k; wi[k] = (c < 58) ? wih[(size_t)o*58 + c] : 0.f; }
  const float bI = bih[o], bH = bhh[o];
  __shared__ float h[128];
  __shared__ float xb[64];
  __shared__ float s_rz[256];
  __shared__ float gin_s[128];
  __shared__ float ghn_s[128];
  if (tid < 128) h[tid] = 0.f;
  if (tid < 64)  xb[tid] = 0.f;
  __syncthreads();
  for (int t=0;t<TDIM;++t){
    const int ttt = dir ? (TDIM-1-t) : t;
    if (tid < 50)      xb[tid] = te[((size_t)n*TDIM + ttt)*50 + tid];
    else if (tid < 58) xb[tid] = cnn[((size_t)n*TDIM + ttt)*8 + (tid - 50)];
    __syncthreads();
    float a0=0,a1=0,a2=0,a3=0;
    const float4* hp = (const float4*)&h[kh*64];
    #pragma unroll
    for (int q=0;q<16;q++){ float4 hv=hp[q];
      a0=fmaf(wh[4*q],hv.x,a0); a1=fmaf(wh[4*q+1],hv.y,a1);
      a2=fmaf(wh[4*q+2],hv.z,a2); a3=fmaf(wh[4*q+3],hv.w,a3); }
    float ah = (a0+a1)+(a2+a3);
    float c0=0,c1=0,c2=0,c3=0;
    const float4* xp = (const float4*)&xb[kh*32];
    #pragma unroll
    for (int q=0;q<8;q++){ float4 xv=xp[q];
      c0=fmaf(wi[4*q],xv.x,c0); c1=fmaf(wi[4*q+1],xv.y,c1);
      c2=fmaf(wi[4*q+2],xv.z,c2); c3=fmaf(wi[4*q+3],xv.w,c3); }
    float ai = (c0+c1)+(c2+c3);
    ah += __shfl_xor(ah, 1);
    ai += __shfl_xor(ai, 1);
    if (kh == 0){
      if (o < 256) s_rz[o] = ah + ai + bI + bH;
      else { gin_s[o-256] = ai + bI; ghn_s[o-256] = ah + bH; }
    }
    __syncthreads();
    if (tid < 128){
      float r  = sigmoidf_(s_rz[tid]);
      float z  = sigmoidf_(s_rz[128+tid]);
      float nn = tanhf_(gin_s[tid] + r*ghn_s[tid]);
      h[tid] = (1.f - z)*nn + z*h[tid];
    }
    __syncthreads();
  }
  if (tid < 128) Hall[(size_t)n*256 + dir*128 + tid] = h[tid];
}

// ---------------- prep ----------------
__global__ __launch_bounds__(256) void k_prep(const float* __restrict__ Hall,
    const float* __restrict__ ctx_w1, const float* __restrict__ proj_w,
    float* __restrict__ a_all, float* __restrict__ s_all){
  const int i = blockIdx.x; const int tid = threadIdx.x;
  __shared__ float hr[256];
  __shared__ float red[2];
  hr[tid] = Hall[(size_t)i*256 + tid];
  __syncthreads();
  if (tid < 128){
    const float4* w  = (const float4*)(ctx_w1 + (size_t)tid*256);
    const float4* hp = (const float4*)hr;
    float a0=0,a1=0,a2=0,a3=0;
    #pragma unroll 8
    for (int q=0;q<64;q++){ float4 wv=w[q], hv=hp[q];
      a0=fmaf(wv.x,hv.x,a0); a1=fmaf(wv.y,hv.y,a1); a2=fmaf(wv.z,hv.z,a2); a3=fmaf(wv.w,hv.w,a3); }
    a_all[(size_t)i*128 + tid] = (a0+a1)+(a2+a3);
  } else {
    const int k = tid - 128;
    float p = hr[k]*proj_w[k] + hr[k+128]*proj_w[k+128];
    #pragma unroll
    for (int off=32; off; off>>=1) p += __shfl_xor(p, off);
    if ((tid & 63) == 0) red[(tid-128)>>6] = p;
  }
  __syncthreads();
  if (tid == 0) s_all[i] = red[0] + red[1];
}

// ---------------- ctx scan v10: v7 base + packed-f32 dots + single-barrier divergent tail ----------------
// v9 lesson: addressable VGPR space is 256 -> 192 pinned floats impossible; 96 (v7) is the max.
// v10 keeps v7's 512thr/K-split-4/96-pinned dot phase but:
//  (1) dots as f32x2 mul-add -> fp-contract fuses to v_pk_fma_f32 (2 FMA/instr, fp32 peak is 2/lane/cyc)
//  (2) ONE barrier/cell: divergent tail in kq==0 lanes (v5-proven), dbuf h, no gate-LDS roundtrip.
__global__ __launch_bounds__(512,2) void k_ctx(
    const float* __restrict__ cg_wih_f, const float* __restrict__ cg_whh_f,
    const float* __restrict__ cg_bih_f, const float* __restrict__ cg_bhh_f,
    const float* __restrict__ cg_wih_b, const float* __restrict__ cg_whh_b,
    const float* __restrict__ cg_bih_b, const float* __restrict__ cg_bhh_b,
    const float* __restrict__ ctx_w2, const float* __restrict__ ctx_b2,
    const float* __restrict__ ctx_w3, const float* __restrict__ proj_b,
    const float* __restrict__ gx0,
    const float* __restrict__ a_all, const float* __restrict__ s_all,
    float* __restrict__ one_d_g, int* __restrict__ flags,
    float* __restrict__ feats){
  const int blk = blockIdx.x;
  const bool isF = blk < 2;
  const int d   = blk & 1;
  const int tid = threadIdx.x;
  const int p   = tid >> 2;      // output row [0,128)
  const int kq  = tid & 3;       // K-quarter: 32 floats
  const float* whh = isF ? cg_whh_f : cg_whh_b;
  const float* wih = isF ? cg_wih_f : cg_wih_b;
  const float* bih = isF ? cg_bih_f : cg_bih_b;
  const float* bhh = isF ? cg_bhh_f : cg_bhh_b;

  // ---- asm-pinned stationary weights: 24 f32x4 = 96 floats (1 row x 3 gates x 32 K)
  const float* wrb = whh + (size_t)(      p)*128 + kq*32;
  const float* wzb = whh + (size_t)(128 + p)*128 + kq*32;
  const float* wnb = whh + (size_t)(256 + p)*128 + kq*32;
  f32x4 wr0=gload4(wrb),    wr1=gload4(wrb+4),  wr2=gload4(wrb+8),  wr3=gload4(wrb+12);
  f32x4 wr4=gload4(wrb+16), wr5=gload4(wrb+20), wr6=gload4(wrb+24), wr7=gload4(wrb+28);
  f32x4 wz0=gload4(wzb),    wz1=gload4(wzb+4),  wz2=gload4(wzb+8),  wz3=gload4(wzb+12);
  f32x4 wz4=gload4(wzb+16), wz5=gload4(wzb+20), wz6=gload4(wzb+24), wz7=gload4(wzb+28);
  f32x4 wn0=gload4(wnb),    wn1=gload4(wnb+4),  wn2=gload4(wnb+8),  wn3=gload4(wnb+12);
  f32x4 wn4=gload4(wnb+16), wn5=gload4(wnb+20), wn6=gload4(wnb+24), wn7=gload4(wnb+28);
  asm volatile("s_waitcnt vmcnt(0)" ::: "memory");
  __builtin_amdgcn_sched_barrier(0);

  // ---- tail scalars (by row p, used in kq==0 lanes), keep-alive blocks remat
  float wir = wih[p],      wiz = wih[128+p], win = wih[256+p];
  float br_ = bih[p]      + bhh[p];
  float bz_ = bih[128+p]  + bhh[128+p];
  float bn_ = bih[256+p];
  float bhn_ = bhh[256+p];
  float pb = proj_b[0];
  asm volatile("" : "+v"(wir), "+v"(wiz), "+v"(win), "+v"(br_), "+v"(bz_),
                    "+v"(bn_), "+v"(bhn_), "+v"(pb));

  __shared__ float hl[2][160];     // 8 chunks of 16 floats, stride 20 (conflict-free), dbuf
  __shared__ float one_d_s[128];
  __shared__ float T_s[160];       // stride-20 chunk layout
  __shared__ float S_s[128];
  __shared__ float red_s[2];

  const float* gsrc = gx0 + (size_t)((isF ? 0 : 2) + d)*128;
  float hm = gsrc[p];              // live in kq==0 lanes
  if (tid < 128) hl[0][(tid>>4)*20 + (tid&15)] = gsrc[tid];
  __syncthreads();

  const int chp = (p>>4)*20 + (p&15);   // row p's h / T_s slot
  const int kb  = kq*40;                // base of K-slice in chunk layout

  for (int i=0;i<NB;++i){
    if (isF){
      // ---- attention (reads hl[0] = h after previous outer step)
      const float* w2r = ctx_w2 + (size_t)p*128 + kq*32;
      const float* w3r = ctx_w3 + (size_t)p*128 + kq*32;
      f32x4 u0=gload4(w2r),    u1=gload4(w2r+4),  u2=gload4(w2r+8),  u3=gload4(w2r+12);
      f32x4 u4=gload4(w2r+16), u5=gload4(w2r+20), u6=gload4(w2r+24), u7=gload4(w2r+28);
      f32x4 v0=gload4(w3r),    v1=gload4(w3r+4),  v2=gload4(w3r+8),  v3=gload4(w3r+12);
      f32x4 v4=gload4(w3r+16), v5=gload4(w3r+20), v6=gload4(w3r+24), v7=gload4(w3r+28);
      asm volatile("s_waitcnt vmcnt(0)" ::: "memory");
      __builtin_amdgcn_sched_barrier(0);
      {
        const f32x4* hA = (const f32x4*)&hl[0][kb];
        const f32x4* hB = (const f32x4*)&hl[0][kb+20];
        f32x4 q0=hA[0],q1=hA[1],q2=hA[2],q3=hA[3];
        f32x4 q4=hB[0],q5=hB[1],q6=hB[2],q7=hB[3];
        float sa=0, sb=0;
        sa=dot4v(sa,u0,q0); sa=dot4v(sa,u1,q1); sa=dot4v(sa,u2,q2); sa=dot4v(sa,u3,q3);
        sb=dot4v(sb,u4,q4); sb=dot4v(sb,u5,q5); sb=dot4v(sb,u6,q6); sb=dot4v(sb,u7,q7);
        float s = sa + sb;
        s += __shfl_xor(s,1); s += __shfl_xor(s,2);
        if (kq == 0) T_s[chp] = tanhf_(a_all[(size_t)i*128 + p] + s + ctx_b2[p]);
      }
      __syncthreads();
      {
        const f32x4* tA = (const f32x4*)&T_s[kb];
        const f32x4* tB = (const f32x4*)&T_s[kb+20];
        f32x4 t0=tA[0],t1=tA[1],t2=tA[2],t3=tA[3];
        f32x4 t4=tB[0],t5=tB[1],t6=tB[2],t7=tB[3];
        float sa=0, sb=0;
        sa=dot4v(sa,v0,t0); sa=dot4v(sa,v1,t1); sa=dot4v(sa,v2,t2); sa=dot4v(sa,v3,t3);
        sb=dot4v(sb,v4,t4); sb=dot4v(sb,v5,t5); sb=dot4v(sb,v6,t6); sb=dot4v(sb,v7,t7);
        float s = sa + sb;
        s += __shfl_xor(s,1); s += __shfl_xor(s,2);
        if (kq == 0) S_s[p] = s;
      }
      __syncthreads();
      if (tid < 64){
        float m = fmaxf(S_s[tid], S_s[tid+64]);
        #pragma unroll
        for (int off=32; off; off>>=1) m = fmaxf(m, __shfl_xor(m, off));
        if (tid == 0) red_s[0] = m;
      }
      __syncthreads();
      if (tid < 128) S_s[tid] = __expf(S_s[tid] - red_s[0]);
      __syncthreads();
      if (tid < 64){
        float s = S_s[tid] + S_s[tid+64];
        #pragma unroll
        for (int off=32; off; off>>=1) s += __shfl_xor(s, off);
        if (tid == 0) red_s[1] = s;
      }
      __syncthreads();
      if (tid < 128){
        float v = (S_s[tid] / red_s[1]) * s_all[i] + pb;
        one_d_s[tid] = v;
        __hip_atomic_store(&one_d_g[((size_t)d*NB + i)*128 + tid], v,
                           __ATOMIC_RELAXED, __HIP_MEMORY_SCOPE_AGENT);
      }
      __syncthreads();
      if (tid == 0){
        __threadfence();
        __hip_atomic_store(&flags[d], i+1, __ATOMIC_RELEASE, __HIP_MEMORY_SCOPE_AGENT);
      }
    } else {
      if (tid == 0){
        while (__hip_atomic_load(&flags[d], __ATOMIC_ACQUIRE, __HIP_MEMORY_SCOPE_AGENT) < i+1){
          __builtin_amdgcn_s_sleep(8);
        }
      }
      __syncthreads();
      if (tid < 128)
        one_d_s[tid] = __hip_atomic_load(&one_d_g[((size_t)d*NB + i)*128 + tid],
                                         __ATOMIC_RELAXED, __HIP_MEMORY_SCOPE_AGENT);
      __syncthreads();
    }
    // ---- inner GRU: 128 cells, ONE barrier each, packed-f32 dots, divergent tail
    for (int tc=0; tc<128; ++tc){
      const float* hcur = hl[tc & 1];
      float*       hnxt = hl[(tc & 1) ^ 1];
      const f32x4* hA = (const f32x4*)&hcur[kb];
      const f32x4* hB = (const f32x4*)&hcur[kb+20];
      f32x4 h0=hA[0],h1=hA[1],h2=hA[2],h3=hA[3];
      f32x4 h4=hB[0],h5=hB[1],h6=hB[2],h7=hB[3];
      f32x2 ar2 = {0.f,0.f}, az2 = {0.f,0.f}, an2 = {0.f,0.f};
      ar2 += wr0.lo*h0.lo; ar2 += wr0.hi*h0.hi; ar2 += wr1.lo*h1.lo; ar2 += wr1.hi*h1.hi;
      ar2 += wr2.lo*h2.lo; ar2 += wr2.hi*h2.hi; ar2 += wr3.lo*h3.lo; ar2 += wr3.hi*h3.hi;
      ar2 += wr4.lo*h4.lo; ar2 += wr4.hi*h4.hi; ar2 += wr5.lo*h5.lo; ar2 += wr5.hi*h5.hi;
      ar2 += wr6.lo*h6.lo; ar2 += wr6.hi*h6.hi; ar2 += wr7.lo*h7.lo; ar2 += wr7.hi*h7.hi;
      az2 += wz0.lo*h0.lo; az2 += wz0.hi*h0.hi; az2 += wz1.lo*h1.lo; az2 += wz1.hi*h1.hi;
      az2 += wz2.lo*h2.lo; az2 += wz2.hi*h2.hi; az2 += wz3.lo*h3.lo; az2 += wz3.hi*h3.hi;
      az2 += wz4.lo*h4.lo; az2 += wz4.hi*h4.hi; az2 += wz5.lo*h5.lo; az2 += wz5.hi*h5.hi;
      az2 += wz6.lo*h6.lo; az2 += wz6.hi*h6.hi; az2 += wz7.lo*h7.lo; az2 += wz7.hi*h7.hi;
      an2 += wn0.lo*h0.lo; an2 += wn0.hi*h0.hi; an2 += wn1.lo*h1.lo; an2 += wn1.hi*h1.hi;
      an2 += wn2.lo*h2.lo; an2 += wn2.hi*h2.hi; an2 += wn3.lo*h3.lo; an2 += wn3.hi*h3.hi;
      an2 += wn4.lo*h4.lo; an2 += wn4.hi*h4.hi; an2 += wn5.lo*h5.lo; an2 += wn5.hi*h5.hi;
      an2 += wn6.lo*h6.lo; an2 += wn6.hi*h6.hi; an2 += wn7.lo*h7.lo; an2 += wn7.hi*h7.hi;
      float ar = ar2.x + ar2.y;
      float az = az2.x + az2.y;
      float an = an2.x + an2.y;
      ar += __shfl_xor(ar,1); ar += __shfl_xor(ar,2);
      az += __shfl_xor(az,1); az += __shfl_xor(az,2);
      an += __shfl_xor(an,1); an += __shfl_xor(an,2);
      if (kq == 0){
        float x = one_d_s[isF ? tc : 127-tc];
        float r  = sigmoidf_(fmaf(x, wir, br_) + ar);
        float z  = sigmoidf_(fmaf(x, wiz, bz_) + az);
        float nn = tanhf_(fmaf(x, win, bn_) + r*(an + bhn_));
        hm = (1.f - z)*nn + z*hm;
        hnxt[chp] = hm;
      }
      __syncthreads();
    }
    if (kq == 0){
      const int off = isF ? d*128 : 256 + d*128;
      feats[(size_t)i*512 + off + p] = hm;
    }
    __syncthreads();
  }
}

// ---------------- classifier ----------------
__global__ __launch_bounds__(256) void k_cls(const float* __restrict__ feats,
    const float* __restrict__ w1, const float* __restrict__ b1,
    const float* __restrict__ w2, const float* __restrict__ b2,
    const float* __restrict__ w3, const float* __restrict__ b3,
    float* __restrict__ out){
  const int n = blockIdx.x; const int tid = threadIdx.x;
  __shared__ float fr[512];
  __shared__ float h1s[256];
  __shared__ float h2s[128];
  fr[tid]       = feats[(size_t)n*512 + tid];
  fr[tid+256]   = feats[(size_t)n*512 + 256 + tid];
  __syncthreads();
  {
    const float4* w  = (const float4*)(w1 + (size_t)tid*512);
    const float4* fp = (const float4*)fr;
    float a0=0,a1=0,a2=0,a3=0;
    #pragma unroll 8
    for (int q=0;q<128;q++){ float4 wv=w[q], fv=fp[q];
      a0=fmaf(wv.x,fv.x,a0); a1=fmaf(wv.y,fv.y,a1); a2=fmaf(wv.z,fv.z,a2); a3=fmaf(wv.w,fv.w,a3); }
    h1s[tid] = lrelu_(b1[tid] + (a0+a1)+(a2+a3));
  }
  __syncthreads();
  if (tid < 128){
    const float4* w  = (const float4*)(w2 + (size_t)tid*256);
    const float4* fp = (const float4*)h1s;
    float a0=0,a1=0,a2=0,a3=0;
    #pragma unroll 8
    for (int q=0;q<64;q++){ float4 wv=w[q], fv=fp[q];
      a0=fmaf(wv.x,fv.x,a0); a1=fmaf(wv.y,fv.y,a1); a2=fmaf(wv.z,fv.z,a2); a3=fmaf(wv.w,fv.w,a3); }
    h2s[tid] = lrelu_(b2[tid] + (a0+a1)+(a2+a3));
  }
  __syncthreads();
  if (tid < NCLS){
    const float4* w  = (const float4*)(w3 + (size_t)tid*128);
    const float4* fp = (const float4*)h2s;
    float a0=0,a1=0,a2=0,a3=0;
    #pragma unroll 8
    for (int q=0;q<32;q++){ float4 wv=w[q], fv=fp[q];
      a0=fmaf(wv.x,fv.x,a0); a1=fmaf(wv.y,fv.y,a1); a2=fmaf(wv.z,fv.z,a2); a3=fmaf(wv.w,fv.w,a3); }
    out[(size_t)n*NCLS + tid] = b3[tid] + (a0+a1)+(a2+a3);
  }
}

// ---------------- workspace layout (bytes) ----------------
#define OFF_FLAGS  0u
#define OFF_SALL   512u
#define OFF_AALL   2048u
#define OFF_ONED   133632u
#define OFF_HALL   395776u
#define OFF_FEATS  657920u
#define OFF_CNN    1182208u
#define OFF_POOL1  1894912u

extern "C" void kernel_launch(void* const* d_in, const int* in_sizes, int n_in,
                              void* d_out, int out_size, void* d_ws, size_t ws_size,
                              hipStream_t stream){
  const float* te   = (const float*)d_in[0];
  const float* tce  = (const float*)d_in[1];
  const float* c1w  = (const float*)d_in[2];
  const float* c1b  = (const float*)d_in[3];
  const float* c2w  = (const float*)d_in[4];
  const float* c2b  = (const float*)d_in[5];
  const float* uwif = (const float*)d_in[6];
  const float* uwhf = (const float*)d_in[7];
  const float* ubif = (const float*)d_in[8];
  const float* ubhf = (const float*)d_in[9];
  const float* uwib = (const float*)d_in[10];
  const float* uwhb = (const float*)d_in[11];
  const float* ubib = (const float*)d_in[12];
  const float* ubhb = (const float*)d_in[13];
  const float* cw1  = (const float*)d_in[14];
  const float* cw2  = (const float*)d_in[15];
  const float* cb2  = (const float*)d_in[16];
  const float* cw3  = (const float*)d_in[17];
  const float* pw   = (const float*)d_in[18];
  const float* pbb  = (const float*)d_in[19];
  const float* gx0  = (const float*)d_in[20];
  const float* gwif = (const float*)d_in[21];
  const float* gwhf = (const float*)d_in[22];
  const float* gbif = (const float*)d_in[23];
  const float* gbhf = (const float*)d_in[24];
  const float* gwib = (const float*)d_in[25];
  const float* gwhb = (const float*)d_in[26];
  const float* gbib = (const float*)d_in[27];
  const float* gbhb = (const float*)d_in[28];
  const float* clw1 = (const float*)d_in[29];
  const float* clb1 = (const float*)d_in[30];
  const float* clw2 = (const float*)d_in[31];
  const float* clb2 = (const float*)d_in[32];
  const float* clw3 = (const float*)d_in[33];
  const float* clb3 = (const float*)d_in[34];
  float* out = (float*)d_out;
  char* ws = (char*)d_ws;
  int*   flags = (int*)  (ws + OFF_FLAGS);
  float* s_all = (float*)(ws + OFF_SALL);
  float* a_all = (float*)(ws + OFF_AALL);
  float* one_d = (float*)(ws + OFF_ONED);
  float* Hall  = (float*)(ws + OFF_HALL);
  float* feats = (float*)(ws + OFF_FEATS);
  float* cnn   = (float*)(ws + OFF_CNN);
  float* pool1 = (float*)(ws + OFF_POOL1);

  hipMemsetAsync(flags, 0, 64, stream);
  k_conv1<<<dim3(NB, TDIM), 256, 0, stream>>>(tce, c1w, c1b, pool1);
  k_conv2<<<dim3(NB, TDIM), 128, 0, stream>>>(pool1, c2w, c2b, cnn);
  k_utt<<<512, 768, 0, stream>>>(te, cnn, uwif, uwhf, ubif, ubhf,
                                 uwib, uwhb, ubib, ubhb, Hall);
  k_prep<<<NB, 256, 0, stream>>>(Hall, cw1, pw, a_all, s_all);
  k_ctx<<<4, 512, 0, stream>>>(gwif, gwhf, gbif, gbhf, gwib, gwhb, gbib, gbhb,
                               cw2, cb2, cw3, pbb, gx0, a_all, s_all,
                               one_d, flags, feats);
  k_cls<<<NB, 256, 0, stream>>>(feats, clw1, clb1, clw2, clb2, clw3, clb3, out);
}